// Round 1
// baseline (93.602 us; speedup 1.0000x reference)
//
#include <hip/hip_runtime.h>

#define NV 1448
#define JD 4344   // 3*NV
#define CC 256
#define BB 64
#define QQ 128    // 2*BB (inputs-batch and targets-batch columns)

// ---------------------------------------------------------------------------
// K1: global average pool over H*W=64 -> latT[c][q], q = t*64+b
// 16 lanes cooperate per (t,b,c) row: fully coalesced 256B segments.
// ---------------------------------------------------------------------------
__global__ __launch_bounds__(256) void pool_kernel(const float* __restrict__ inp,
                                                   const float* __restrict__ tgt,
                                                   float* __restrict__ latT) {
    int gid  = blockIdx.x * 256 + threadIdx.x;   // 524288 threads total
    int lane = gid & 15;
    int row  = gid >> 4;                          // (t,b,c) flat, 32768 rows
    if (row >= 2 * BB * CC) return;
    int t  = row >> 14;                           // BB*CC = 16384
    int bc = row & 16383;
    const float* src = (t ? tgt : inp) + (size_t)bc * 64;
    float4 v = reinterpret_cast<const float4*>(src)[lane];
    float s = (v.x + v.y) + (v.z + v.w);
    s += __shfl_xor(s, 1);
    s += __shfl_xor(s, 2);
    s += __shfl_xor(s, 4);
    s += __shfl_xor(s, 8);
    if (lane == 0) {
        int b = bc >> 8, c = bc & 255;
        latT[c * QQ + t * BB + b] = s * (1.0f / 64.0f);
    }
}

// ---------------------------------------------------------------------------
// K2: decode GEMM  pts3[q][j] = sum_c delta_L[j][c]*latT[c][q] + mu_L[j]
// Only stored when labels[b] matches the block's label L -> every cell written
// exactly once, no atomics, no memset.
// Block: (jtile of 32 rows, label). 512 threads: jl = tid&31, qg = tid>>5
// (16 groups x 8 q's). K staged in LDS chunks of 32.
// ---------------------------------------------------------------------------
__global__ __launch_bounds__(512) void decode_kernel(const float* __restrict__ latT,
                                                     const float* __restrict__ muL,
                                                     const float* __restrict__ deltaL,
                                                     const float* __restrict__ muR,
                                                     const float* __restrict__ deltaR,
                                                     const int* __restrict__ labels,
                                                     float* __restrict__ pts3) {
    const int jt = blockIdx.x;                 // 136 tiles
    const int L  = blockIdx.y;                 // 0=left, 1=right
    const float* __restrict__ delta = L ? deltaR : deltaL;
    const float* __restrict__ mu    = L ? muR : muL;
    const int j0  = jt * 32;
    const int tid = threadIdx.x;
    const int jl  = tid & 31;
    const int qg  = tid >> 5;                  // 0..15

    __shared__ float As[32][36];               // [j][k], padded (36*4=144B, 16B-aligned rows)
    __shared__ float Bs[32][QQ];               // [k][q]

    float acc[8];
#pragma unroll
    for (int i = 0; i < 8; ++i) acc[i] = 0.f;

    for (int kc = 0; kc < CC; kc += 32) {
        __syncthreads();
        if (tid < 256) {                        // stage A: 32 rows x 32 k
            int r = tid >> 3;                   // 0..31
            int i = tid & 7;                    // float4 index 0..7
            int j = j0 + r;
            float4 v = make_float4(0.f, 0.f, 0.f, 0.f);
            if (j < JD)
                v = *reinterpret_cast<const float4*>(delta + (size_t)j * CC + kc + i * 4);
            *reinterpret_cast<float4*>(&As[r][i * 4]) = v;
        }
        {                                       // stage B: 32 x 128 floats = 1024 float4
            const float4* src = reinterpret_cast<const float4*>(latT + (size_t)kc * QQ);
            float4* dst = reinterpret_cast<float4*>(&Bs[0][0]);
            dst[tid]       = src[tid];
            dst[tid + 512] = src[tid + 512];
        }
        __syncthreads();

#pragma unroll
        for (int k4 = 0; k4 < 32; k4 += 4) {
            float4 av = *reinterpret_cast<const float4*>(&As[jl][k4]);
            float a[4] = {av.x, av.y, av.z, av.w};
#pragma unroll
            for (int kk = 0; kk < 4; ++kk) {
                const float4* bp = reinterpret_cast<const float4*>(&Bs[k4 + kk][qg * 8]);
                float4 b0 = bp[0], b1 = bp[1];
                float ak = a[kk];
                acc[0] = fmaf(ak, b0.x, acc[0]);
                acc[1] = fmaf(ak, b0.y, acc[1]);
                acc[2] = fmaf(ak, b0.z, acc[2]);
                acc[3] = fmaf(ak, b0.w, acc[3]);
                acc[4] = fmaf(ak, b1.x, acc[4]);
                acc[5] = fmaf(ak, b1.y, acc[5]);
                acc[6] = fmaf(ak, b1.z, acc[6]);
                acc[7] = fmaf(ak, b1.w, acc[7]);
            }
        }
    }

    int j = j0 + jl;
    if (j < JD) {
        float base = mu[j];
#pragma unroll
        for (int i = 0; i < 8; ++i) {
            int q = qg * 8 + i;
            int b = q & 63;
            if (labels[b] == L) pts3[(size_t)q * JD + j] = acc[i] + base;
        }
    }
}

// ---------------------------------------------------------------------------
// K2b: pack points as float4(x,y,z,|p|^2)
// ---------------------------------------------------------------------------
__global__ __launch_bounds__(256) void pack_kernel(const float* __restrict__ pts3,
                                                   float4* __restrict__ pts4) {
    int gid = blockIdx.x * 256 + threadIdx.x;   // QQ*NV = 185344 = 724*256
    if (gid >= QQ * NV) return;
    int tb = gid / NV;
    int n  = gid - tb * NV;
    const float* p = pts3 + (size_t)tb * JD + n * 3;
    float x = p[0], y = p[1], z = p[2];
    pts4[gid] = make_float4(x, y, z, fmaf(x, x, fmaf(y, y, z * z)));
}

// ---------------------------------------------------------------------------
// K3: chamfer row-mins. grid (chunk 0..2, b 0..63, dir 0..1).
// dir=0: rows of pts_in vs pts_tg (dist_1); dir=1: swapped (dist_2).
// B-side staged in LDS (23KB), inner reads are wave-broadcast.
// 2 rows per thread amortize the LDS read; min over d^2, sqrt after.
// ---------------------------------------------------------------------------
__global__ __launch_bounds__(256) void chamfer_kernel(const float4* __restrict__ pts4,
                                                      float* __restrict__ partials) {
    const int chunk = blockIdx.x;
    const int b     = blockIdx.y;
    const int dir   = blockIdx.z;
    const float4* __restrict__ Ap = pts4 + (size_t)(dir * BB + b) * NV;
    const float4* __restrict__ Bp = pts4 + (size_t)((1 - dir) * BB + b) * NV;

    __shared__ float4 Bs[NV];
    for (int i = threadIdx.x; i < NV; i += 256) Bs[i] = Bp[i];
    __syncthreads();

    int r0 = chunk * 512 + threadIdx.x;
    int r1 = r0 + 256;
    float4 a0 = (r0 < NV) ? Ap[r0] : make_float4(0.f, 0.f, 0.f, 0.f);
    float4 a1 = (r1 < NV) ? Ap[r1] : make_float4(0.f, 0.f, 0.f, 0.f);
    float m0 = 1e30f, m1 = 1e30f;

#pragma unroll 4
    for (int m = 0; m < NV; ++m) {
        float4 bv = Bs[m];
        float d0 = fmaf(a0.x, bv.x, fmaf(a0.y, bv.y, a0.z * bv.z));
        float d1 = fmaf(a1.x, bv.x, fmaf(a1.y, bv.y, a1.z * bv.z));
        float s0 = a0.w + bv.w;
        float s1 = a1.w + bv.w;
        m0 = fminf(m0, fmaf(-2.f, d0, s0));
        m1 = fminf(m1, fmaf(-2.f, d1, s1));
    }

    float v0 = (r0 < NV) ? sqrtf(fmaxf(m0, 1e-12f)) : 0.f;
    float v1 = (r1 < NV) ? sqrtf(fmaxf(m1, 1e-12f)) : 0.f;
    float s = v0 + v1;
    s += __shfl_xor(s, 1);
    s += __shfl_xor(s, 2);
    s += __shfl_xor(s, 4);
    s += __shfl_xor(s, 8);
    s += __shfl_xor(s, 16);
    s += __shfl_xor(s, 32);

    __shared__ float wsum[4];
    if ((threadIdx.x & 63) == 0) wsum[threadIdx.x >> 6] = s;
    __syncthreads();
    if (threadIdx.x == 0)
        partials[(blockIdx.z * 64 + blockIdx.y) * 3 + blockIdx.x] =
            wsum[0] + wsum[1] + wsum[2] + wsum[3];
}

// ---------------------------------------------------------------------------
// K4: final reduce of 384 partials -> scalar mean sum
// ---------------------------------------------------------------------------
__global__ __launch_bounds__(256) void finalize_kernel(const float* __restrict__ partials,
                                                       float* __restrict__ out) {
    int tid = threadIdx.x;
    float s = 0.f;
    for (int i = tid; i < 384; i += 256) s += partials[i];
    s += __shfl_xor(s, 1);
    s += __shfl_xor(s, 2);
    s += __shfl_xor(s, 4);
    s += __shfl_xor(s, 8);
    s += __shfl_xor(s, 16);
    s += __shfl_xor(s, 32);
    __shared__ float wsum[4];
    if ((tid & 63) == 0) wsum[tid >> 6] = s;
    __syncthreads();
    if (tid == 0)
        out[0] = (wsum[0] + wsum[1] + wsum[2] + wsum[3]) * (1.0f / (64.0f * 1448.0f));
}

extern "C" void kernel_launch(void* const* d_in, const int* in_sizes, int n_in,
                              void* d_out, int out_size, void* d_ws, size_t ws_size,
                              hipStream_t stream) {
    const float* inp    = (const float*)d_in[0];
    const float* tgt    = (const float*)d_in[1];
    const int*   labels = (const int*)d_in[2];
    const float* muL    = (const float*)d_in[3];
    const float* deltaL = (const float*)d_in[4];
    const float* muR    = (const float*)d_in[5];
    const float* deltaR = (const float*)d_in[6];
    float* out = (float*)d_out;

    char* ws = (char*)d_ws;
    float*  latT     = (float*)ws;                               // 256*128*4   = 128 KB
    float*  pts3     = (float*)(ws + (128 << 10));               // 128*4344*4  = 2224128 B
    float4* pts4     = (float4*)(ws + (128 << 10) + 2224128);    // 128*1448*16 = 2965504 B
    float*  partials = (float*)((char*)pts4 + (size_t)QQ * NV * sizeof(float4)); // 384*4 B

    hipLaunchKernelGGL(pool_kernel, dim3(2048), dim3(256), 0, stream, inp, tgt, latT);
    hipLaunchKernelGGL(decode_kernel, dim3(136, 2, 1), dim3(512), 0, stream,
                       latT, muL, deltaL, muR, deltaR, labels, pts3);
    hipLaunchKernelGGL(pack_kernel, dim3((QQ * NV + 255) / 256), dim3(256), 0, stream,
                       pts3, pts4);
    hipLaunchKernelGGL(chamfer_kernel, dim3(3, 64, 2), dim3(256), 0, stream,
                       pts4, partials);
    hipLaunchKernelGGL(finalize_kernel, dim3(1), dim3(256), 0, stream, partials, out);
}

// Round 2
// 73.113 us; speedup vs baseline: 1.2802x; 1.2802x over previous
//
#include <hip/hip_runtime.h>

#define NV 1448
#define JD 4344   // 3*NV
#define CC 256
#define BB 64
#define QQ 128    // 2*BB (inputs-batch and targets-batch columns)
#define HALF 724  // NV/2, columns per chamfer block
#define NROW (2 * BB * NV)  // 185344 total row-slots (dir x b x row)

// ---------------------------------------------------------------------------
// K1: global average pool over H*W=64 -> latT[c][q], q = t*64+b
// ---------------------------------------------------------------------------
__global__ __launch_bounds__(256) void pool_kernel(const float* __restrict__ inp,
                                                   const float* __restrict__ tgt,
                                                   float* __restrict__ latT) {
    int gid  = blockIdx.x * 256 + threadIdx.x;
    int lane = gid & 15;
    int row  = gid >> 4;                          // (t,b,c) flat, 32768 rows
    if (row >= 2 * BB * CC) return;
    int t  = row >> 14;                           // BB*CC = 16384
    int bc = row & 16383;
    const float* src = (t ? tgt : inp) + (size_t)bc * 64;
    float4 v = reinterpret_cast<const float4*>(src)[lane];
    float s = (v.x + v.y) + (v.z + v.w);
    s += __shfl_xor(s, 1);
    s += __shfl_xor(s, 2);
    s += __shfl_xor(s, 4);
    s += __shfl_xor(s, 8);
    if (lane == 0) {
        int b = bc >> 8, c = bc & 255;
        latT[c * QQ + t * BB + b] = s * (1.0f / 64.0f);
    }
}

// ---------------------------------------------------------------------------
// K2: decode GEMM  pts3[q][j] = sum_c delta_L[j][c]*latT[c][q] + mu_L[j]
// ---------------------------------------------------------------------------
__global__ __launch_bounds__(512) void decode_kernel(const float* __restrict__ latT,
                                                     const float* __restrict__ muL,
                                                     const float* __restrict__ deltaL,
                                                     const float* __restrict__ muR,
                                                     const float* __restrict__ deltaR,
                                                     const int* __restrict__ labels,
                                                     float* __restrict__ pts3) {
    const int jt = blockIdx.x;                 // 136 tiles
    const int L  = blockIdx.y;                 // 0=left, 1=right
    const float* __restrict__ delta = L ? deltaR : deltaL;
    const float* __restrict__ mu    = L ? muR : muL;
    const int j0  = jt * 32;
    const int tid = threadIdx.x;
    const int jl  = tid & 31;
    const int qg  = tid >> 5;                  // 0..15

    __shared__ float As[32][36];
    __shared__ float Bs[32][QQ];

    float acc[8];
#pragma unroll
    for (int i = 0; i < 8; ++i) acc[i] = 0.f;

    for (int kc = 0; kc < CC; kc += 32) {
        __syncthreads();
        if (tid < 256) {                        // stage A: 32 rows x 32 k
            int r = tid >> 3;
            int i = tid & 7;
            int j = j0 + r;
            float4 v = make_float4(0.f, 0.f, 0.f, 0.f);
            if (j < JD)
                v = *reinterpret_cast<const float4*>(delta + (size_t)j * CC + kc + i * 4);
            *reinterpret_cast<float4*>(&As[r][i * 4]) = v;
        }
        {                                       // stage B: 32 x 128 floats
            const float4* src = reinterpret_cast<const float4*>(latT + (size_t)kc * QQ);
            float4* dst = reinterpret_cast<float4*>(&Bs[0][0]);
            dst[tid]       = src[tid];
            dst[tid + 512] = src[tid + 512];
        }
        __syncthreads();

#pragma unroll
        for (int k4 = 0; k4 < 32; k4 += 4) {
            float4 av = *reinterpret_cast<const float4*>(&As[jl][k4]);
            float a[4] = {av.x, av.y, av.z, av.w};
#pragma unroll
            for (int kk = 0; kk < 4; ++kk) {
                const float4* bp = reinterpret_cast<const float4*>(&Bs[k4 + kk][qg * 8]);
                float4 b0 = bp[0], b1 = bp[1];
                float ak = a[kk];
                acc[0] = fmaf(ak, b0.x, acc[0]);
                acc[1] = fmaf(ak, b0.y, acc[1]);
                acc[2] = fmaf(ak, b0.z, acc[2]);
                acc[3] = fmaf(ak, b0.w, acc[3]);
                acc[4] = fmaf(ak, b1.x, acc[4]);
                acc[5] = fmaf(ak, b1.y, acc[5]);
                acc[6] = fmaf(ak, b1.z, acc[6]);
                acc[7] = fmaf(ak, b1.w, acc[7]);
            }
        }
    }

    int j = j0 + jl;
    if (j < JD) {
        float base = mu[j];
#pragma unroll
        for (int i = 0; i < 8; ++i) {
            int q = qg * 8 + i;
            int b = q & 63;
            if (labels[b] == L) pts3[(size_t)q * JD + j] = acc[i] + base;
        }
    }
}

// ---------------------------------------------------------------------------
// K2b: pack points as float4(x,y,z,|p|^2)
// ---------------------------------------------------------------------------
__global__ __launch_bounds__(256) void pack_kernel(const float* __restrict__ pts3,
                                                   float4* __restrict__ pts4) {
    int gid = blockIdx.x * 256 + threadIdx.x;   // QQ*NV = 185344 = 724*256
    if (gid >= QQ * NV) return;
    int tb = gid / NV;
    int n  = gid - tb * NV;
    const float* p = pts3 + (size_t)tb * JD + n * 3;
    float x = p[0], y = p[1], z = p[2];
    pts4[gid] = make_float4(x, y, z, fmaf(x, x, fmaf(y, y, z * z)));
}

// ---------------------------------------------------------------------------
// K3: chamfer partial row-mins over half the columns.
// grid (chunk 0..2, b 0..63, z 0..3: dir = z>>1, half = z&1); 768 blocks
// = exactly 3 blocks/CU, 12 waves/CU. B-half staged in LDS pre-scaled as
// (-2x,-2y,-2z,|b|^2) -> d^2 = fma(bx,ax, fma(by,ay, fma(bz,az, aw+bw))).
// 2 rows/thread, 2 min-accumulators/row to break the fmin chain.
// ---------------------------------------------------------------------------
__global__ __launch_bounds__(256) void chamfer_kernel(const float4* __restrict__ pts4,
                                                      float* __restrict__ pmin) {
    const int chunk = blockIdx.x;
    const int b     = blockIdx.y;
    const int dir   = blockIdx.z >> 1;
    const int half  = blockIdx.z & 1;
    const float4* __restrict__ Ap = pts4 + (size_t)(dir * BB + b) * NV;
    const float4* __restrict__ Bp = pts4 + (size_t)((1 - dir) * BB + b) * NV + half * HALF;

    __shared__ float4 Bs[HALF];
    for (int i = threadIdx.x; i < HALF; i += 256) {
        float4 v = Bp[i];
        Bs[i] = make_float4(-2.f * v.x, -2.f * v.y, -2.f * v.z, v.w);
    }
    __syncthreads();

    int r0 = chunk * 512 + threadIdx.x;
    int r1 = r0 + 256;
    float4 a0 = (r0 < NV) ? Ap[r0] : make_float4(0.f, 0.f, 0.f, 0.f);
    float4 a1 = (r1 < NV) ? Ap[r1] : make_float4(0.f, 0.f, 0.f, 0.f);
    float m0a = 1e30f, m0b = 1e30f, m1a = 1e30f, m1b = 1e30f;

#pragma unroll 2
    for (int m = 0; m < HALF; m += 2) {
        float4 b0 = Bs[m];
        float4 b1 = Bs[m + 1];
        float d00 = fmaf(b0.x, a0.x, fmaf(b0.y, a0.y, fmaf(b0.z, a0.z, a0.w + b0.w)));
        float d10 = fmaf(b0.x, a1.x, fmaf(b0.y, a1.y, fmaf(b0.z, a1.z, a1.w + b0.w)));
        m0a = fminf(m0a, d00);
        m1a = fminf(m1a, d10);
        float d01 = fmaf(b1.x, a0.x, fmaf(b1.y, a0.y, fmaf(b1.z, a0.z, a0.w + b1.w)));
        float d11 = fmaf(b1.x, a1.x, fmaf(b1.y, a1.y, fmaf(b1.z, a1.z, a1.w + b1.w)));
        m0b = fminf(m0b, d01);
        m1b = fminf(m1b, d11);
    }

    float m0 = fminf(m0a, m0b);
    float m1 = fminf(m1a, m1b);
    size_t base = (size_t)half * NROW + (size_t)(dir * BB + b) * NV;
    if (r0 < NV) pmin[base + r0] = m0;
    if (r1 < NV) pmin[base + r1] = m1;
}

// ---------------------------------------------------------------------------
// K3b: combine halves, sqrt, per-block sums. 362 blocks x 256 thr x 2 rows
// = 185344 rows exactly.
// ---------------------------------------------------------------------------
__global__ __launch_bounds__(256) void combine_kernel(const float* __restrict__ pmin,
                                                      float* __restrict__ partials) {
    int g0 = blockIdx.x * 512 + threadIdx.x;
    int g1 = g0 + 256;
    float v0 = sqrtf(fmaxf(fminf(pmin[g0], pmin[g0 + NROW]), 1e-12f));
    float v1 = sqrtf(fmaxf(fminf(pmin[g1], pmin[g1 + NROW]), 1e-12f));
    float s = v0 + v1;
    s += __shfl_xor(s, 1);
    s += __shfl_xor(s, 2);
    s += __shfl_xor(s, 4);
    s += __shfl_xor(s, 8);
    s += __shfl_xor(s, 16);
    s += __shfl_xor(s, 32);
    __shared__ float wsum[4];
    if ((threadIdx.x & 63) == 0) wsum[threadIdx.x >> 6] = s;
    __syncthreads();
    if (threadIdx.x == 0)
        partials[blockIdx.x] = wsum[0] + wsum[1] + wsum[2] + wsum[3];
}

// ---------------------------------------------------------------------------
// K4: final reduce of 362 partials -> scalar
// ---------------------------------------------------------------------------
__global__ __launch_bounds__(256) void finalize_kernel(const float* __restrict__ partials,
                                                       float* __restrict__ out) {
    int tid = threadIdx.x;
    float s = 0.f;
    for (int i = tid; i < 362; i += 256) s += partials[i];
    s += __shfl_xor(s, 1);
    s += __shfl_xor(s, 2);
    s += __shfl_xor(s, 4);
    s += __shfl_xor(s, 8);
    s += __shfl_xor(s, 16);
    s += __shfl_xor(s, 32);
    __shared__ float wsum[4];
    if ((tid & 63) == 0) wsum[tid >> 6] = s;
    __syncthreads();
    if (tid == 0)
        out[0] = (wsum[0] + wsum[1] + wsum[2] + wsum[3]) * (1.0f / (64.0f * 1448.0f));
}

extern "C" void kernel_launch(void* const* d_in, const int* in_sizes, int n_in,
                              void* d_out, int out_size, void* d_ws, size_t ws_size,
                              hipStream_t stream) {
    const float* inp    = (const float*)d_in[0];
    const float* tgt    = (const float*)d_in[1];
    const int*   labels = (const int*)d_in[2];
    const float* muL    = (const float*)d_in[3];
    const float* deltaL = (const float*)d_in[4];
    const float* muR    = (const float*)d_in[5];
    const float* deltaR = (const float*)d_in[6];
    float* out = (float*)d_out;

    char* ws = (char*)d_ws;
    float*  latT     = (float*)ws;                               // 256*128*4   = 128 KB
    float*  pts3     = (float*)(ws + (128 << 10));               // 128*4344*4  = 2224128 B
    float4* pts4     = (float4*)(ws + (128 << 10) + 2224128);    // 128*1448*16 = 2965504 B
    // pmin overlays pts3 (dead after pack): 2*185344*4 = 1482752 B <= 2224128 B
    float*  pmin     = pts3;
    // partials overlays latT (dead after decode): 362*4 B
    float*  partials = latT;

    hipLaunchKernelGGL(pool_kernel, dim3(2048), dim3(256), 0, stream, inp, tgt, latT);
    hipLaunchKernelGGL(decode_kernel, dim3(136, 2, 1), dim3(512), 0, stream,
                       latT, muL, deltaL, muR, deltaR, labels, pts3);
    hipLaunchKernelGGL(pack_kernel, dim3((QQ * NV + 255) / 256), dim3(256), 0, stream,
                       pts3, pts4);
    hipLaunchKernelGGL(chamfer_kernel, dim3(3, 64, 4), dim3(256), 0, stream,
                       pts4, pmin);
    hipLaunchKernelGGL(combine_kernel, dim3(362), dim3(256), 0, stream, pmin, partials);
    hipLaunchKernelGGL(finalize_kernel, dim3(1), dim3(256), 0, stream, partials, out);
}

// Round 3
// 68.302 us; speedup vs baseline: 1.3704x; 1.0704x over previous
//
#include <hip/hip_runtime.h>

#define NV 1448
#define JD 4344   // 3*NV
#define CC 256
#define BB 64
#define QQ 128    // 2*BB (inputs-batch and targets-batch columns)
#define QCOLS 362 // NV/4, columns per chamfer block
#define NROW (2 * BB * NV)  // 185344 total row-slots (dir x b x row)

// ---------------------------------------------------------------------------
// K1: global average pool over H*W=64 -> latT[c][q], q = t*64+b
// ---------------------------------------------------------------------------
__global__ __launch_bounds__(256) void pool_kernel(const float* __restrict__ inp,
                                                   const float* __restrict__ tgt,
                                                   float* __restrict__ latT) {
    int gid  = blockIdx.x * 256 + threadIdx.x;
    int lane = gid & 15;
    int row  = gid >> 4;                          // (t,b,c) flat, 32768 rows
    if (row >= 2 * BB * CC) return;
    int t  = row >> 14;                           // BB*CC = 16384
    int bc = row & 16383;
    const float* src = (t ? tgt : inp) + (size_t)bc * 64;
    float4 v = reinterpret_cast<const float4*>(src)[lane];
    float s = (v.x + v.y) + (v.z + v.w);
    s += __shfl_xor(s, 1);
    s += __shfl_xor(s, 2);
    s += __shfl_xor(s, 4);
    s += __shfl_xor(s, 8);
    if (lane == 0) {
        int b = bc >> 8, c = bc & 255;
        latT[c * QQ + t * BB + b] = s * (1.0f / 64.0f);
    }
}

// ---------------------------------------------------------------------------
// K2: decode GEMM  pts3[q][j] = sum_c delta_L[j][c]*latT[c][q] + mu_L[j]
// ---------------------------------------------------------------------------
__global__ __launch_bounds__(512) void decode_kernel(const float* __restrict__ latT,
                                                     const float* __restrict__ muL,
                                                     const float* __restrict__ deltaL,
                                                     const float* __restrict__ muR,
                                                     const float* __restrict__ deltaR,
                                                     const int* __restrict__ labels,
                                                     float* __restrict__ pts3) {
    const int jt = blockIdx.x;                 // 136 tiles
    const int L  = blockIdx.y;                 // 0=left, 1=right
    const float* __restrict__ delta = L ? deltaR : deltaL;
    const float* __restrict__ mu    = L ? muR : muL;
    const int j0  = jt * 32;
    const int tid = threadIdx.x;
    const int jl  = tid & 31;
    const int qg  = tid >> 5;                  // 0..15

    __shared__ float As[32][36];
    __shared__ float Bs[32][QQ];

    float acc[8];
#pragma unroll
    for (int i = 0; i < 8; ++i) acc[i] = 0.f;

    for (int kc = 0; kc < CC; kc += 32) {
        __syncthreads();
        if (tid < 256) {                        // stage A: 32 rows x 32 k
            int r = tid >> 3;
            int i = tid & 7;
            int j = j0 + r;
            float4 v = make_float4(0.f, 0.f, 0.f, 0.f);
            if (j < JD)
                v = *reinterpret_cast<const float4*>(delta + (size_t)j * CC + kc + i * 4);
            *reinterpret_cast<float4*>(&As[r][i * 4]) = v;
        }
        {                                       // stage B: 32 x 128 floats
            const float4* src = reinterpret_cast<const float4*>(latT + (size_t)kc * QQ);
            float4* dst = reinterpret_cast<float4*>(&Bs[0][0]);
            dst[tid]       = src[tid];
            dst[tid + 512] = src[tid + 512];
        }
        __syncthreads();

#pragma unroll
        for (int k4 = 0; k4 < 32; k4 += 4) {
            float4 av = *reinterpret_cast<const float4*>(&As[jl][k4]);
            float a[4] = {av.x, av.y, av.z, av.w};
#pragma unroll
            for (int kk = 0; kk < 4; ++kk) {
                const float4* bp = reinterpret_cast<const float4*>(&Bs[k4 + kk][qg * 8]);
                float4 b0 = bp[0], b1 = bp[1];
                float ak = a[kk];
                acc[0] = fmaf(ak, b0.x, acc[0]);
                acc[1] = fmaf(ak, b0.y, acc[1]);
                acc[2] = fmaf(ak, b0.z, acc[2]);
                acc[3] = fmaf(ak, b0.w, acc[3]);
                acc[4] = fmaf(ak, b1.x, acc[4]);
                acc[5] = fmaf(ak, b1.y, acc[5]);
                acc[6] = fmaf(ak, b1.z, acc[6]);
                acc[7] = fmaf(ak, b1.w, acc[7]);
            }
        }
    }

    int j = j0 + jl;
    if (j < JD) {
        float base = mu[j];
#pragma unroll
        for (int i = 0; i < 8; ++i) {
            int q = qg * 8 + i;
            int b = q & 63;
            if (labels[b] == L) pts3[(size_t)q * JD + j] = acc[i] + base;
        }
    }
}

// ---------------------------------------------------------------------------
// K2b: pack points as float4(x,y,z,|p|^2)
// ---------------------------------------------------------------------------
__global__ __launch_bounds__(256) void pack_kernel(const float* __restrict__ pts3,
                                                   float4* __restrict__ pts4) {
    int gid = blockIdx.x * 256 + threadIdx.x;   // QQ*NV = 185344 = 724*256
    if (gid >= QQ * NV) return;
    int tb = gid / NV;
    int n  = gid - tb * NV;
    const float* p = pts3 + (size_t)tb * JD + n * 3;
    float x = p[0], y = p[1], z = p[2];
    pts4[gid] = make_float4(x, y, z, fmaf(x, x, fmaf(y, y, z * z)));
}

// ---------------------------------------------------------------------------
// K3: chamfer partial row-mins over a quarter of the columns.
// grid (chunk 0..2, b 0..63, z 0..7: dir = z>>2, q = z&3); 1536 blocks
// = 6 blocks/CU, 24 waves/CU. B staged in LDS as (-2x,-2y,-2z,|b|^2);
// min over d' = fma(bx,ax, fma(by,ay, fma(bz,az, bw)))  (a.w added at end,
// outside the loop). 2 rows/thread, min3-fused accumulate: 3.5 VALU/pair.
// ---------------------------------------------------------------------------
__global__ __launch_bounds__(256) void chamfer_kernel(const float4* __restrict__ pts4,
                                                      float* __restrict__ pmin) {
    const int chunk = blockIdx.x;
    const int b     = blockIdx.y;
    const int dir   = blockIdx.z >> 2;
    const int q     = blockIdx.z & 3;
    const float4* __restrict__ Ap = pts4 + (size_t)(dir * BB + b) * NV;
    const float4* __restrict__ Bp = pts4 + (size_t)((1 - dir) * BB + b) * NV + q * QCOLS;

    __shared__ float4 Bs[QCOLS];
    for (int i = threadIdx.x; i < QCOLS; i += 256) {
        float4 v = Bp[i];
        Bs[i] = make_float4(-2.f * v.x, -2.f * v.y, -2.f * v.z, v.w);
    }
    __syncthreads();

    int r0 = chunk * 512 + threadIdx.x;
    int r1 = r0 + 256;
    float4 a0 = (r0 < NV) ? Ap[r0] : make_float4(0.f, 0.f, 0.f, 0.f);
    float4 a1 = (r1 < NV) ? Ap[r1] : make_float4(0.f, 0.f, 0.f, 0.f);
    float m0 = 1e30f, m1 = 1e30f;

#pragma unroll 2
    for (int m = 0; m < QCOLS; m += 2) {
        float4 b0 = Bs[m];
        float4 b1 = Bs[m + 1];
        float d00 = fmaf(b0.x, a0.x, fmaf(b0.y, a0.y, fmaf(b0.z, a0.z, b0.w)));
        float d01 = fmaf(b1.x, a0.x, fmaf(b1.y, a0.y, fmaf(b1.z, a0.z, b1.w)));
        m0 = fminf(fminf(m0, d00), d01);          // -> v_min3_f32
        float d10 = fmaf(b0.x, a1.x, fmaf(b0.y, a1.y, fmaf(b0.z, a1.z, b0.w)));
        float d11 = fmaf(b1.x, a1.x, fmaf(b1.y, a1.y, fmaf(b1.z, a1.z, b1.w)));
        m1 = fminf(fminf(m1, d10), d11);
    }

    size_t base = (size_t)q * NROW + (size_t)(dir * BB + b) * NV;
    if (r0 < NV) pmin[base + r0] = m0 + a0.w;     // restore the |a|^2 term
    if (r1 < NV) pmin[base + r1] = m1 + a1.w;
}

// ---------------------------------------------------------------------------
// K3b: combine 4 quarter-mins, sqrt, per-block sums. 362 blocks x 256 x 2.
// ---------------------------------------------------------------------------
__global__ __launch_bounds__(256) void combine_kernel(const float* __restrict__ pmin,
                                                      float* __restrict__ partials) {
    int g0 = blockIdx.x * 512 + threadIdx.x;
    int g1 = g0 + 256;
    float v0 = fminf(fminf(pmin[g0], pmin[g0 + NROW]),
                     fminf(pmin[g0 + 2 * NROW], pmin[g0 + 3 * NROW]));
    float v1 = fminf(fminf(pmin[g1], pmin[g1 + NROW]),
                     fminf(pmin[g1 + 2 * NROW], pmin[g1 + 3 * NROW]));
    float s = sqrtf(fmaxf(v0, 1e-12f)) + sqrtf(fmaxf(v1, 1e-12f));
    s += __shfl_xor(s, 1);
    s += __shfl_xor(s, 2);
    s += __shfl_xor(s, 4);
    s += __shfl_xor(s, 8);
    s += __shfl_xor(s, 16);
    s += __shfl_xor(s, 32);
    __shared__ float wsum[4];
    if ((threadIdx.x & 63) == 0) wsum[threadIdx.x >> 6] = s;
    __syncthreads();
    if (threadIdx.x == 0)
        partials[blockIdx.x] = wsum[0] + wsum[1] + wsum[2] + wsum[3];
}

// ---------------------------------------------------------------------------
// K4: final reduce of 362 partials -> scalar
// ---------------------------------------------------------------------------
__global__ __launch_bounds__(256) void finalize_kernel(const float* __restrict__ partials,
                                                       float* __restrict__ out) {
    int tid = threadIdx.x;
    float s = 0.f;
    for (int i = tid; i < 362; i += 256) s += partials[i];
    s += __shfl_xor(s, 1);
    s += __shfl_xor(s, 2);
    s += __shfl_xor(s, 4);
    s += __shfl_xor(s, 8);
    s += __shfl_xor(s, 16);
    s += __shfl_xor(s, 32);
    __shared__ float wsum[4];
    if ((tid & 63) == 0) wsum[tid >> 6] = s;
    __syncthreads();
    if (tid == 0)
        out[0] = (wsum[0] + wsum[1] + wsum[2] + wsum[3]) * (1.0f / (64.0f * 1448.0f));
}

extern "C" void kernel_launch(void* const* d_in, const int* in_sizes, int n_in,
                              void* d_out, int out_size, void* d_ws, size_t ws_size,
                              hipStream_t stream) {
    const float* inp    = (const float*)d_in[0];
    const float* tgt    = (const float*)d_in[1];
    const int*   labels = (const int*)d_in[2];
    const float* muL    = (const float*)d_in[3];
    const float* deltaL = (const float*)d_in[4];
    const float* muR    = (const float*)d_in[5];
    const float* deltaR = (const float*)d_in[6];
    float* out = (float*)d_out;

    char* ws = (char*)d_ws;
    float*  latT = (float*)ws;                               // 256*128*4   = 128 KB
    float*  pts3 = (float*)(ws + (128 << 10));               // 128*4344*4  = 2224128 B
    float4* pts4 = (float4*)(ws + (128 << 10) + 2224128);    // 128*1448*16 = 2965504 B
    float*  pmin = (float*)((char*)pts4 + (size_t)QQ * NV * sizeof(float4)); // 4*185344*4 = 2965504 B
    float*  partials = latT;   // latT dead after decode; 362*4 B

    hipLaunchKernelGGL(pool_kernel, dim3(2048), dim3(256), 0, stream, inp, tgt, latT);
    hipLaunchKernelGGL(decode_kernel, dim3(136, 2, 1), dim3(512), 0, stream,
                       latT, muL, deltaL, muR, deltaR, labels, pts3);
    hipLaunchKernelGGL(pack_kernel, dim3((QQ * NV + 255) / 256), dim3(256), 0, stream,
                       pts3, pts4);
    hipLaunchKernelGGL(chamfer_kernel, dim3(3, 64, 8), dim3(256), 0, stream,
                       pts4, pmin);
    hipLaunchKernelGGL(combine_kernel, dim3(362), dim3(256), 0, stream, pmin, partials);
    hipLaunchKernelGGL(finalize_kernel, dim3(1), dim3(256), 0, stream, partials, out);
}